// Round 10
// baseline (17209.938 us; speedup 1.0000x reference)
//
#include <hip/hip_runtime.h>

// DA-RNN persistent kernel, round 12: 2 co-resident blocks/CU.
// R9 post-mortem: FETCH collapsed (5.98 GB) but dur barely moved -> no longer
// HBM-bound. VALUBusy 44%, occupancy 48% (1 block/CU): 56% of time is barrier
// drain + phase latency with nothing else to run. This round: BB=2, grid 512,
// 80 KB LDS/block (64 KB u1 = k<128 half of uexT/udmT + 16 KB wk) -> exactly
// 2 blocks x 80 KB = 160 KB, 2048 threads/CU. The 64-VGPR compiler pin is
// exactly the 8-waves/SIMD budget -> no spill risk. Block A's compute overlaps
// block B's barriers. HBM streams unchanged vs R9; L2 weight stream doubles
// (concurrent, overlappable - NOT R8's serialized 2-pass). wk fits 16 KB by
// reading Ve/Vd from global (L1 broadcast) + register c-states (R9 trick).
// Math identical to R8/R9 (both passed, absmax 9.77e-4).

#define B_   1024
#define T_   128     // T_ENCO
#define NI_  128     // N_INP
#define H_   256     // N_HID
#define H4_  1024    // 4*N_HID
#define TD_  24      // T_DECO
#define DS_  30      // decoder steps
#define BB   2       // batch rows per workgroup
#define TB   1024    // threads per block
#define LDS_BYTES 81920u   // 16 KB wk + 64 KB u1; 2 blocks/CU = 160 KB

typedef _Float16 hf_t;
typedef _Float16 half8  __attribute__((ext_vector_type(8)));
typedef _Float16 half2v __attribute__((ext_vector_type(2)));

__device__ __forceinline__ float sigm(float x) {
    return __builtin_amdgcn_rcpf(1.0f + __expf(-x));
}
__device__ __forceinline__ float tanh_f(float x) {
    float e = __expf(2.0f * x);
    return 1.0f - 2.0f * __builtin_amdgcn_rcpf(e + 1.0f);
}
__device__ __forceinline__ float fdot2f(half2v a, half2v b, float c) {
#if __has_builtin(__builtin_amdgcn_fdot2)
    return __builtin_amdgcn_fdot2(a, b, c, false);
#else
    return fmaf((float)a.x, (float)b.x, fmaf((float)a.y, (float)b.y, c));
#endif
}
__device__ __forceinline__ float dot8h(half8 w, half8 x, float acc) {
    acc = fdot2f(__builtin_shufflevector(w, w, 0, 1), __builtin_shufflevector(x, x, 0, 1), acc);
    acc = fdot2f(__builtin_shufflevector(w, w, 2, 3), __builtin_shufflevector(x, x, 2, 3), acc);
    acc = fdot2f(__builtin_shufflevector(w, w, 4, 5), __builtin_shufflevector(x, x, 4, 5), acc);
    acc = fdot2f(__builtin_shufflevector(w, w, 6, 7), __builtin_shufflevector(x, x, 6, 7), acc);
    return acc;
}
__device__ __forceinline__ hf_t nt_load_h(const hf_t* p) {
#if __has_builtin(__builtin_nontemporal_load)
    return __builtin_nontemporal_load(p);
#else
    return *p;
#endif
}
__device__ __forceinline__ void nt_store_h(hf_t v, hf_t* p) {
#if __has_builtin(__builtin_nontemporal_store)
    __builtin_nontemporal_store(v, p);
#else
    *p = v;
#endif
}

// ---- f16 weight layout inside d_ws (offsets in halves) ----
#define W_WE    0u
#define W_UE2   131072u
#define W_EWIH  163840u
#define W_EWHH  294912u
#define W_MWIH  557056u
#define W_MWHH  819200u
#define W_DWIH  1081344u
#define W_DWHH  1343488u
#define W_WD    1605632u
#define W_UD    1736704u
#define SCR_A   2097152u       // upper halves: uexT k>=128 -> udmT o>=128 [b][0..127][j]
#define SCR_B   35651584u      // midb [b][t][k]

__global__ void convw_kernel(const float* __restrict__ sWE, const float* __restrict__ sUE2,
                             const float* __restrict__ sEI, const float* __restrict__ sEH,
                             const float* __restrict__ sMI, const float* __restrict__ sMH,
                             const float* __restrict__ sDI, const float* __restrict__ sDH,
                             const float* __restrict__ sWD, const float* __restrict__ sUD,
                             hf_t* __restrict__ dst) {
    const int gtid = blockIdx.x * blockDim.x + threadIdx.x;
    const int gs   = gridDim.x * blockDim.x;
    for (int n = gtid; n < 131072; n += gs) {       // WE'
        int e = n & 7, q = n >> 3, k = q & 255, c = q >> 8, kq = c >> 4, i = c & 15;
        dst[W_WE + n] = (hf_t)sWE[k * 512 + kq * 128 + i * 8 + e];
    }
    for (int n = gtid; n < 32768; n += gs) {        // UE2'
        int e = n & 7, q = n >> 3, k = q & 255, c = q >> 8, kq = c >> 2, i = c & 3;
        dst[W_UE2 + n] = (hf_t)sUE2[k * 128 + kq * 32 + i * 8 + e];
    }
    for (int n = gtid; n < 131072; n += gs) {       // EWIH' (K=128)
        int e = n & 7, q = n >> 3, o = q & 1023, i = q >> 10;
        dst[W_EWIH + n] = (hf_t)sEI[o * 128 + i * 8 + e];
    }
    for (int n = gtid; n < 262144; n += gs) {       // K=256 gates
        int e = n & 7, q = n >> 3, o = q & 1023, i = q >> 10;
        int s = o * 256 + i * 8 + e;
        dst[W_EWHH + n] = (hf_t)sEH[s];
        dst[W_MWIH + n] = (hf_t)sMI[s];
        dst[W_MWHH + n] = (hf_t)sMH[s];
        dst[W_DWIH + n] = (hf_t)sDI[s];
        dst[W_DWHH + n] = (hf_t)sDH[s];
    }
    for (int n = gtid; n < 131072; n += gs) {       // WD'
        int e = n & 7, q = n >> 3, k = q & 255, c = q >> 8, kq = c >> 4, i = c & 15;
        dst[W_WD + n] = (hf_t)sWD[k * 512 + kq * 128 + i * 8 + e];
    }
    for (int n = gtid; n < 65536; n += gs)          // UD plain
        dst[W_UD + n] = (hf_t)sUD[n];
}

// ---- wk offsets (floats, wk = sm[0..4096) = 16 KB) ----
#define O_HC    0        // hf [2][512]                       512f
#define O_HM    512      // hf [2][256] (decoder: dinh)       256f
#define O_XRAW  768      // f32 [2][128]                      256f
#define O_XHG   1024     // hf [2][128]  xh then xg           128f
#define O_HCXI  1152     // f32 [2][256]                      512f
#define O_RED   1664     // f32 [16] output-reduce partials
#define O_GBUF  2048     // f32 [2048] gates / partials / scores / sbuf
// phase-0 X staging reuses wk[0..4096) as f32[128][32] quarters

__global__ __launch_bounds__(TB, 8) void dsrnn_kernel(
    const float* __restrict__ inp,
    const float* __restrict__ UeW,  const float* __restrict__ Ueb,
    const float* __restrict__ Ue2b,
    const float* __restrict__ Web,
    const float* __restrict__ VeW,  const float* __restrict__ Veb,
    const float* __restrict__ Udb,
    const float* __restrict__ Wdb,
    const float* __restrict__ VdW,  const float* __restrict__ Vdb,
    const float* __restrict__ ebih, const float* __restrict__ ebhh,
    const float* __restrict__ mbih, const float* __restrict__ mbhh,
    const float* __restrict__ dbih, const float* __restrict__ dbhh,
    const float* __restrict__ rW,   const float* __restrict__ rb,
    const hf_t* __restrict__ wb,
    hf_t* __restrict__ scrA,
    hf_t* __restrict__ scrB,
    float* __restrict__ out)
{
    extern __shared__ float sm[];
    float* wk = sm;                       // 4096 floats = 16 KB
    hf_t*  u1 = (hf_t*)(sm + 4096);       // 32768 halves = 64 KB

    const int tid = threadIdx.x;
    const int b0  = blockIdx.x * BB;

    hf_t*  hc   = (hf_t*)(wk + O_HC);
    hf_t*  hm   = (hf_t*)(wk + O_HM);
    float* xraw = wk + O_XRAW;
    hf_t*  xhg  = (hf_t*)(wk + O_XHG);
    float* hcxi = wk + O_HCXI;
    float* red  = wk + O_RED;
    float* gbuf = wk + O_GBUF;
    hf_t*  dinh = (hf_t*)(wk + O_HM);     // decoder alias of HM

    // ---------- Phase 0: uexT; k<128 -> LDS u1, k>=128 -> scrA (nt) ----------
    // X staged in f32 [128][32] j-quarters (16 KB), exact f32 accumulate.
    {
        const int jj = tid & 31;        // j within quarter
        const int kg = tid >> 5;        // 32 groups x 8 k
        for (int b = 0; b < BB; ++b) {
            const float* Xg = inp + (size_t)(b0 + b) * T_ * NI_;
            for (int jq = 0; jq < 4; ++jq) {
                __syncthreads();
                for (int i = tid; i < 128 * 32; i += TB) {
                    int t = i >> 5, j2 = i & 31;
                    wk[i] = Xg[t * NI_ + jq * 32 + j2];
                }
                __syncthreads();
                const int j = jq * 32 + jj;
                for (int k = kg * 8; k < kg * 8 + 8; ++k) {
                    const float* wrow = UeW + (size_t)k * T_;
                    float acc = Ueb[k];
#pragma unroll 4
                    for (int t = 0; t < T_; ++t) acc = fmaf(wrow[t], wk[t * 32 + jj], acc);
                    if (k < 128)
                        u1[((size_t)(b * 128) + k) * 128 + j] = (hf_t)acc;
                    else
                        nt_store_h((hf_t)acc,
                                   scrA + (((size_t)(b0 + b) * 128) + (k - 128)) * 128 + j);
                }
            }
        }
    }
    __syncthreads();
    for (int i = tid; i < 768; i += TB) wk[i] = 0.0f;    // zero hc + hm
    __syncthreads();

    float c_enc = 0.0f, c_mid = 0.0f;   // f32 c-states in regs, (b,k)=tid<512

    // ---------- Fused encoder + mid loop ----------
    for (int t = 0; t < T_; ++t) {
        // (a) load x_t
        if (tid < 256) {
            const int b = tid >> 7, j = tid & 127;
            float v = inp[((size_t)(b0 + b) * T_ + t) * NI_ + j];
            xraw[b * NI_ + j] = v;
            xhg[b * NI_ + j]  = (hf_t)v;
        }
        __syncthreads();

        // (b) We.[h;c] + Ue2.x partials, k-quarter split, 2 batches
        {
            const int k = tid & 255, kq = tid >> 8;
            const half8* wWE = (const half8*)(wb + W_WE)  + (size_t)(kq * 16) * 256 + k;
            const half8* wU2 = (const half8*)(wb + W_UE2) + (size_t)(kq * 4)  * 256 + k;
            float a0 = 0.f, a1 = 0.f;
#pragma unroll 8
            for (int i = 0; i < 16; ++i) {
                half8 w = wWE[(size_t)i * 256];
                a0 = dot8h(w, *(const half8*)&hc[0 * 512 + kq * 128 + i * 8], a0);
                a1 = dot8h(w, *(const half8*)&hc[1 * 512 + kq * 128 + i * 8], a1);
            }
#pragma unroll
            for (int i = 0; i < 4; ++i) {
                half8 w = wU2[(size_t)i * 256];
                a0 = dot8h(w, *(const half8*)&xhg[0 * 128 + kq * 32 + i * 8], a0);
                a1 = dot8h(w, *(const half8*)&xhg[1 * 128 + kq * 32 + i * 8], a1);
            }
            gbuf[kq * 512 + 0 * 256 + k] = a0;
            gbuf[kq * 512 + 1 * 256 + k] = a1;
        }
        __syncthreads();
        if (tid < 512) {
            const int b = tid >> 8, k = tid & 255;
            hcxi[b * 256 + k] = gbuf[b * 256 + k] + gbuf[512 + b * 256 + k]
                              + gbuf[1024 + b * 256 + k] + gbuf[1536 + b * 256 + k]
                              + Web[k] + Ue2b[k];
        }
        __syncthreads();

        // (c) scores: kq 0,1 from LDS u1; kq 2,3 from HBM scrA (nt)
        {
            const int b = tid >> 9, kq = (tid >> 7) & 3, j = tid & 127;
            const float* hx = hcxi + b * 256 + kq * 64;
            const float* vw = VeW + kq * 64;
            float acc = (kq == 0) ? Veb[0] : 0.f;
            if (kq < 2) {
                const hf_t* up = u1 + ((size_t)(b * 128 + kq * 64)) * 128 + j;
#pragma unroll 8
                for (int k2 = 0; k2 < 64; ++k2) {
                    float u = (float)up[(size_t)k2 * 128];
                    acc = fmaf(vw[k2], tanh_f(hx[k2] + u), acc);
                }
            } else {
                const hf_t* up = scrA + ((size_t)(b0 + b) * 128 + (kq - 2) * 64) * 128 + j;
#pragma unroll 8
                for (int k2 = 0; k2 < 64; ++k2) {
                    float u = (float)nt_load_h(up + (size_t)k2 * 128);
                    acc = fmaf(vw[k2], tanh_f(hx[k2] + u), acc);
                }
            }
            gbuf[b * 512 + kq * 128 + j] = acc;
        }
        __syncthreads();

        // (d) softmax per b (one wave per b), gate x
        if (tid < 128) {
            const int b = tid >> 6, lane = tid & 63;
            const int base = b << 9;
            float sA = gbuf[base + lane]       + gbuf[base + 128 + lane]
                     + gbuf[base + 256 + lane] + gbuf[base + 384 + lane];
            float sB = gbuf[base + 64 + lane]  + gbuf[base + 192 + lane]
                     + gbuf[base + 320 + lane] + gbuf[base + 448 + lane];
            float m = fmaxf(sA, sB);
            for (int d = 1; d < 64; d <<= 1) m = fmaxf(m, __shfl_xor(m, d));
            float eA = __expf(sA - m), eB = __expf(sB - m);
            float ssum = eA + eB;
            for (int d = 1; d < 64; d <<= 1) ssum += __shfl_xor(ssum, d);
            float inv = 1.0f / ssum;
            xhg[b * NI_ + lane]      = (hf_t)(xraw[b * NI_ + lane] * eA * inv);
            xhg[b * NI_ + lane + 64] = (hf_t)(xraw[b * NI_ + lane + 64] * eB * inv);
        }
        __syncthreads();

        // (e) encoder gates: thread o owns row o (read exactly once)
        {
            const int o = tid;
            const half8* wih = (const half8*)(wb + W_EWIH) + o;
            const half8* whh = (const half8*)(wb + W_EWHH) + o;
            float bias = ebih[o] + ebhh[o];
            float a0 = bias, a1 = bias;
#pragma unroll 8
            for (int i = 0; i < 16; ++i) {
                half8 w = wih[(size_t)i * 1024];
                a0 = dot8h(w, *(const half8*)&xhg[0 * 128 + i * 8], a0);
                a1 = dot8h(w, *(const half8*)&xhg[1 * 128 + i * 8], a1);
            }
#pragma unroll 8
            for (int i = 0; i < 32; ++i) {
                half8 w = whh[(size_t)i * 1024];
                a0 = dot8h(w, *(const half8*)&hc[0 * 512 + i * 8], a0);
                a1 = dot8h(w, *(const half8*)&hc[1 * 512 + i * 8], a1);
            }
            gbuf[0 * 1024 + o] = a0; gbuf[1 * 1024 + o] = a1;
        }
        __syncthreads();

        // (f) encoder LSTM update (c in register)
        if (tid < 512) {
            const int b = tid >> 8, k = tid & 255;
            float gi = gbuf[b * H4_ + k];
            float gf = gbuf[b * H4_ + H_ + k];
            float gg = gbuf[b * H4_ + 2 * H_ + k];
            float go = gbuf[b * H4_ + 3 * H_ + k];
            float c2 = sigm(gf) * c_enc + sigm(gi) * tanh_f(gg);
            float h2 = sigm(go) * tanh_f(c2);
            c_enc = c2;
            hc[b * 512 + k]       = (hf_t)h2;
            hc[b * 512 + 256 + k] = (hf_t)c2;
        }
        __syncthreads();

        // (g) mid gates
        {
            const int o = tid;
            const half8* wih = (const half8*)(wb + W_MWIH) + o;
            const half8* whh = (const half8*)(wb + W_MWHH) + o;
            float bias = mbih[o] + mbhh[o];
            float a0 = bias, a1 = bias;
#pragma unroll 8
            for (int i = 0; i < 32; ++i) {
                half8 w = wih[(size_t)i * 1024];
                a0 = dot8h(w, *(const half8*)&hc[0 * 512 + i * 8], a0);
                a1 = dot8h(w, *(const half8*)&hc[1 * 512 + i * 8], a1);
            }
#pragma unroll 8
            for (int i = 0; i < 32; ++i) {
                half8 w = whh[(size_t)i * 1024];
                a0 = dot8h(w, *(const half8*)&hm[0 * 256 + i * 8], a0);
                a1 = dot8h(w, *(const half8*)&hm[1 * 256 + i * 8], a1);
            }
            gbuf[0 * 1024 + o] = a0; gbuf[1 * 1024 + o] = a1;
        }
        __syncthreads();

        // (h) mid LSTM update + store mid (c in register)
        if (tid < 512) {
            const int b = tid >> 8, k = tid & 255;
            float gi = gbuf[b * H4_ + k];
            float gf = gbuf[b * H4_ + H_ + k];
            float gg = gbuf[b * H4_ + 2 * H_ + k];
            float go = gbuf[b * H4_ + 3 * H_ + k];
            float c2 = sigm(gf) * c_mid + sigm(gi) * tanh_f(gg);
            float h2 = sigm(go) * tanh_f(c2);
            c_mid = c2;
            hm[b * 256 + k] = (hf_t)h2;
            scrB[((size_t)(b0 + b) * T_ + t) * H_ + k] = (hf_t)h2;
        }
        __syncthreads();
    }

    // ---------- udm pass: o<128 -> LDS u1, o>=128 -> scrA (nt) ----------
    // b(2) x oq(4) x tt(128); 64 o per thread; mid rows L1/L2-served.
    {
        const int b = tid >> 9, r = tid & 511, oq = r >> 7, tt = r & 127;
        const half8* mrow = (const half8*)(scrB + ((size_t)(b0 + b) * T_ + tt) * H_);
        const half8* udw = (const half8*)(wb + W_UD);
        for (int o2 = 0; o2 < 64; ++o2) {
            const int o = oq * 64 + o2;
            const half8* ur = udw + (size_t)o * 32;
            float acc = Udb[o];
#pragma unroll 8
            for (int i = 0; i < 32; ++i) acc = dot8h(ur[i], mrow[i], acc);
            if (o < 128)
                u1[((size_t)(b * 128) + o) * 128 + tt] = (hf_t)acc;
            else
                nt_store_h((hf_t)acc,
                           scrA + (((size_t)(b0 + b) * 128) + (o - 128)) * 128 + tt);
        }
    }
    __syncthreads();
    for (int i = tid; i < 512; i += TB) wk[i] = 0.0f;    // zero dec hc
    __syncthreads();

    float c_dec = 0.0f;

    // ---------- Decoder ----------
    for (int s = 0; s < DS_; ++s) {
        // (a') Wd.[h;c] partials, k-quarter split
        {
            const int k = tid & 255, kq = tid >> 8;
            const half8* wWD = (const half8*)(wb + W_WD) + (size_t)(kq * 16) * 256 + k;
            float a0 = 0.f, a1 = 0.f;
#pragma unroll 8
            for (int i = 0; i < 16; ++i) {
                half8 w = wWD[(size_t)i * 256];
                a0 = dot8h(w, *(const half8*)&hc[0 * 512 + kq * 128 + i * 8], a0);
                a1 = dot8h(w, *(const half8*)&hc[1 * 512 + kq * 128 + i * 8], a1);
            }
            gbuf[kq * 512 + 0 * 256 + k] = a0;
            gbuf[kq * 512 + 1 * 256 + k] = a1;
        }
        __syncthreads();
        if (tid < 512) {
            const int b = tid >> 8, k = tid & 255;
            hcxi[b * 256 + k] = gbuf[b * 256 + k] + gbuf[512 + b * 256 + k]
                              + gbuf[1024 + b * 256 + k] + gbuf[1536 + b * 256 + k]
                              + Wdb[k];
        }
        __syncthreads();

        // (b') temporal scores: kq 0,1 LDS u1; kq 2,3 HBM scrA (nt)
        {
            const int b = tid >> 9, kq = (tid >> 7) & 3, j = tid & 127;
            const float* hx = hcxi + b * 256 + kq * 64;
            const float* vw = VdW + kq * 64;
            float acc = (kq == 0) ? Vdb[0] : 0.f;
            if (kq < 2) {
                const hf_t* up = u1 + ((size_t)(b * 128 + kq * 64)) * 128 + j;
#pragma unroll 8
                for (int k2 = 0; k2 < 64; ++k2) {
                    float u = (float)up[(size_t)k2 * 128];
                    acc = fmaf(vw[k2], tanh_f(hx[k2] + u), acc);
                }
            } else {
                const hf_t* up = scrA + ((size_t)(b0 + b) * 128 + (kq - 2) * 64) * 128 + j;
#pragma unroll 8
                for (int k2 = 0; k2 < 64; ++k2) {
                    float u = (float)nt_load_h(up + (size_t)k2 * 128);
                    acc = fmaf(vw[k2], tanh_f(hx[k2] + u), acc);
                }
            }
            gbuf[b * 512 + kq * 128 + j] = acc;
        }
        __syncthreads();
        if (tid < 256) {   // sbuf = gbuf[1024..1280)
            const int b = tid >> 7, j = tid & 127;
            const int base = b << 9;
            gbuf[1024 + b * 128 + j] = gbuf[base + j] + gbuf[base + 128 + j]
                                     + gbuf[base + 256 + j] + gbuf[base + 384 + j];
        }
        __syncthreads();

        // (d') dec_in partials -> gbuf[0..1024) (score region, dead now)
        {
            const int b = tid >> 9, jh = (tid >> 8) & 1, h = tid & 255;
            const hf_t* mp = scrB + (size_t)(b0 + b) * T_ * H_ + h;
            const float* sb = gbuf + 1024 + b * 128 + jh * 64;
            float acc = 0.0f;
            const int jbase = jh * 64;
            for (int j = 0; j < 64; ++j)
                acc = fmaf(sb[j], (float)mp[(size_t)(jbase + j) * H_], acc);
            gbuf[(b * 2 + jh) * 256 + h] = acc;
        }
        __syncthreads();
        if (tid < 512) {
            const int b = tid >> 8, h = tid & 255;
            dinh[b * 256 + h] = (hf_t)(gbuf[b * 512 + h] + gbuf[b * 512 + 256 + h]);
        }
        __syncthreads();

        // (e') decoder gates
        {
            const int o = tid;
            const half8* wih = (const half8*)(wb + W_DWIH) + o;
            const half8* whh = (const half8*)(wb + W_DWHH) + o;
            float bias = dbih[o] + dbhh[o];
            float a0 = bias, a1 = bias;
#pragma unroll 8
            for (int i = 0; i < 32; ++i) {
                half8 w = wih[(size_t)i * 1024];
                a0 = dot8h(w, *(const half8*)&dinh[0 * 256 + i * 8], a0);
                a1 = dot8h(w, *(const half8*)&dinh[1 * 256 + i * 8], a1);
            }
#pragma unroll 8
            for (int i = 0; i < 32; ++i) {
                half8 w = whh[(size_t)i * 1024];
                a0 = dot8h(w, *(const half8*)&hc[0 * 512 + i * 8], a0);
                a1 = dot8h(w, *(const half8*)&hc[1 * 512 + i * 8], a1);
            }
            gbuf[0 * 1024 + o] = a0; gbuf[1 * 1024 + o] = a1;
        }
        __syncthreads();

        // (f') decoder LSTM update (c in register), keep h2 for (g')
        float h2dec = 0.0f;
        if (tid < 512) {
            const int b = tid >> 8, k = tid & 255;
            float gi = gbuf[b * H4_ + k];
            float gf = gbuf[b * H4_ + H_ + k];
            float gg = gbuf[b * H4_ + 2 * H_ + k];
            float go = gbuf[b * H4_ + 3 * H_ + k];
            float c2 = sigm(gf) * c_dec + sigm(gi) * tanh_f(gg);
            h2dec = sigm(go) * tanh_f(c2);
            c_dec = c2;
            hc[b * 512 + k]       = (hf_t)h2dec;
            hc[b * 512 + 256 + k] = (hf_t)c2;
        }
        __syncthreads();

        // (g') out[b, s-6] = rW.h + rb  (wave shuffle reduce)
        if (s >= 6 && tid < 512) {
            const int k = tid & 255;
            float p = rW[k] * h2dec;
            for (int d = 1; d < 64; d <<= 1) p += __shfl_xor(p, d);
            if ((tid & 63) == 0) red[tid >> 6] = p;   // red[w], w = 0..7
        }
        __syncthreads();
        if (s >= 6 && tid < 2) {
            float v = red[tid * 4] + red[tid * 4 + 1]
                    + red[tid * 4 + 2] + red[tid * 4 + 3] + rb[0];
            out[(size_t)(b0 + tid) * TD_ + (s - 6)] = v;
        }
        __syncthreads();
    }
}

extern "C" void kernel_launch(void* const* d_in, const int* in_sizes, int n_in,
                              void* d_out, int out_size, void* d_ws, size_t ws_size,
                              hipStream_t stream) {
    const float* inp  = (const float*)d_in[0];
    const float* UeW  = (const float*)d_in[2];
    const float* Ueb  = (const float*)d_in[3];
    const float* Ue2W = (const float*)d_in[4];
    const float* Ue2b = (const float*)d_in[5];
    const float* WeW  = (const float*)d_in[6];
    const float* Web  = (const float*)d_in[7];
    const float* VeW  = (const float*)d_in[8];
    const float* Veb  = (const float*)d_in[9];
    const float* UdW  = (const float*)d_in[10];
    const float* Udb  = (const float*)d_in[11];
    const float* WdW  = (const float*)d_in[12];
    const float* Wdb  = (const float*)d_in[13];
    const float* VdW  = (const float*)d_in[14];
    const float* Vdb  = (const float*)d_in[15];
    const float* eWih = (const float*)d_in[16];
    const float* eWhh = (const float*)d_in[17];
    const float* ebih = (const float*)d_in[18];
    const float* ebhh = (const float*)d_in[19];
    const float* mWih = (const float*)d_in[20];
    const float* mWhh = (const float*)d_in[21];
    const float* mbih = (const float*)d_in[22];
    const float* mbhh = (const float*)d_in[23];
    const float* dWih = (const float*)d_in[24];
    const float* dWhh = (const float*)d_in[25];
    const float* dbih = (const float*)d_in[26];
    const float* dbhh = (const float*)d_in[27];
    const float* rW   = (const float*)d_in[28];
    const float* rb   = (const float*)d_in[29];

    hf_t* wsb  = (hf_t*)d_ws;
    hf_t* scrA = wsb + SCR_A;
    hf_t* scrB = wsb + SCR_B;

    // allow 80 KB dynamic LDS (one-time attribute; host-side, graph-safe)
    static bool attr_set = false;
    if (!attr_set) {
        hipFuncSetAttribute((const void*)dsrnn_kernel,
                            hipFuncAttributeMaxDynamicSharedMemorySize, LDS_BYTES);
        attr_set = true;
    }

    convw_kernel<<<512, 256, 0, stream>>>(WeW, Ue2W, eWih, eWhh, mWih, mWhh,
                                          dWih, dWhh, WdW, UdW, wsb);

    dsrnn_kernel<<<B_ / BB, TB, LDS_BYTES, stream>>>(
        inp, UeW, Ueb, Ue2b, Web, VeW, Veb, Udb, Wdb, VdW, Vdb,
        ebih, ebhh, mbih, mbhh, dbih, dbhh, rW, rb,
        wsb, scrA, scrB, (float*)d_out);
}